// Round 6
// baseline (486.293 us; speedup 1.0000x reference)
//
#include <hip/hip_runtime.h>

#define HH 512
#define WW 512
#define RR 5
#define KS 11
#define EPS_F 1e-5f
#define NLOG2E 1.44269504088896340736f
#define TW 64                  // tile width (blockDim.x)
#define THY 4                  // blockDim.y
#define ROWS 2                 // output rows per thread (mild coarsening)
#define TILE_H (THY * ROWS)    // 8 output rows per block
#define LW (TW + 2 * RR)       // 74
#define LH (TILE_H + 2 * RR)   // 18
#define PLANE (LH * LW)        // 1332 floats per LDS plane

// R6: R5's no-spill structure + (a) image channels staged in LDS (hot loop is
// pure ds_read with immediate offsets -> no global addr VALU, 69 TB/s pipe
// instead of 39 TB/s L1), (b) ROWS=2: 12x11 neighbor window shared by 2 output
// rows -> neighbor loads/pixel 121 -> 66, squarings amortized 2x.
// Lessons enforced: scalar accumulators only (8), all indexing compile-time,
// no heavy coarsening (R3/R4 spilled), masked-t makes OOB weights 0 with no
// per-tap masks (only e=0 tap is the always-valid center).
__global__ __launch_bounds__(256) void gauss_psf_kernel(const float* __restrict__ image,
                                                        const float* __restrict__ psf,
                                                        float* __restrict__ out) {
    __shared__ float sh[4 * PLANE];   // t | img0 | img1 | img2  (21.3 KB)

    const int tx  = threadIdx.x;            // 0..63
    const int ty  = threadIdx.y;            // 0..3
    const int tid = ty * 64 + tx;
    const int bx0 = blockIdx.x * TW;
    const int by0 = blockIdx.y * TILE_H;
    const int b   = blockIdx.z;

    const float* pw   = psf + (size_t)b * HH * WW;
    const float* img0 = image + (size_t)b * 3 * HH * WW;
    const float* img1 = img0 + HH * WW;
    const float* img2 = img0 + 2 * HH * WW;

    // ---- Phase 1: fill masked-t tile + 3 clamped image tiles ----
#pragma unroll
    for (int base = 0; base < PLANE; base += 256) {
        const int idx = base + tid;
        if (idx < PLANE) {
            const int row = idx / LW, col = idx - row * LW;
            const int gy = by0 - RR + row, gx = bx0 - RR + col;
            const bool in = ((unsigned)gy < (unsigned)HH) && ((unsigned)gx < (unsigned)WW);
            const int cy = gy < 0 ? 0 : (gy > HH - 1 ? HH - 1 : gy);
            const int cx = gx < 0 ? 0 : (gx > WW - 1 ? WW - 1 : gx);
            const int gi = cy * WW + cx;
            const float w = pw[gi];
            const float a = -NLOG2E * __builtin_amdgcn_rcpf(fmaf(2.0f * w, w, EPS_F));
            sh[idx]             = in ? __builtin_amdgcn_exp2f(a) : 0.0f;  // masked t
            sh[PLANE + idx]     = img0[gi];   // clamped img (weight 0 kills OOB)
            sh[2 * PLANE + idx] = img1[gi];
            sh[3 * PLANE + idx] = img2[gi];
        }
    }
    __syncthreads();

    // ---- Phase 2: 12x11 window -> 2 output rows, all reads from LDS ----
    const int x  = bx0 + tx;
    const int y0 = by0 + ty * ROWS;
    const int lbase = ty * ROWS * LW + tx;   // tile addr of (y0-RR, x-RR)+... row 0 col tx

    float a0[ROWS], a1[ROWS], a2[ROWS], aw[ROWS];
#pragma unroll
    for (int o = 0; o < ROWS; ++o) { a0[o] = a1[o] = a2[o] = 0.0f; aw[o] = 0.0f; }

#pragma unroll
    for (int r = 0; r < ROWS + 2 * RR; ++r) {        // 12 neighbor rows
#pragma unroll
        for (int j = 0; j < KS; ++j) {               // 11 neighbor cols
            const int off = lbase + r * LW + j;      // const-offset ds_reads
            const float t  = sh[off];
            const float i0 = sh[PLANE + off];
            const float i1 = sh[2 * PLANE + off];
            const float i2 = sh[3 * PLANE + off];

            const float T2 = t * t, T4 = T2 * T2, T8 = T4 * T4,
                        T16 = T8 * T8, T32 = T16 * T16;
            const int jj = (j - RR) * (j - RR);      // constexpr after unroll

#pragma unroll
            for (int o = 0; o < ROWS; ++o) {         // constant bounds
                const int iv = r - RR - o;           // constexpr
                if (iv * iv <= RR * RR) {            // constexpr guard
                    const int e = iv * iv + jj;      // 0..50, constexpr
                    float p = 1.0f;
                    if (e & 1)  p *= t;
                    if (e & 2)  p *= T2;
                    if (e & 4)  p *= T4;
                    if (e & 8)  p *= T8;
                    if (e & 16) p *= T16;
                    if (e & 32) p *= T32;
                    aw[o] += p;
                    a0[o] = fmaf(i0, p, a0[o]);
                    a1[o] = fmaf(i1, p, a1[o]);
                    a2[o] = fmaf(i2, p, a2[o]);
                }
            }
        }
    }

    float* outb = out + (size_t)b * 3 * HH * WW;
#pragma unroll
    for (int o = 0; o < ROWS; ++o) {
        const float s = aw[o];                       // >= 1 (center tap = 1)
        float inv = __builtin_amdgcn_rcpf(s);
        inv = inv * (2.0f - s * inv);                // Newton: ~1e-7 rel
        const int oi = (y0 + o) * WW + x;
        outb[oi]               = a0[o] * inv;
        outb[HH * WW + oi]     = a1[o] * inv;
        outb[2 * HH * WW + oi] = a2[o] * inv;
    }
}

extern "C" void kernel_launch(void* const* d_in, const int* in_sizes, int n_in,
                              void* d_out, int out_size, void* d_ws, size_t ws_size,
                              hipStream_t stream) {
    const float* image = (const float*)d_in[0];
    const float* psf   = (const float*)d_in[1];
    float* out = (float*)d_out;

    dim3 block(TW, THY, 1);
    dim3 grid(WW / TW, HH / TILE_H, 4);   // 8 x 64 x 4 = 2048 blocks, 8192 waves
    gauss_psf_kernel<<<grid, block, 0, stream>>>(image, psf, out);
}

// Round 7
// 88.665 us; speedup vs baseline: 5.4846x; 5.4846x over previous
//
#include <hip/hip_runtime.h>

#define HH 512
#define WW 512
#define RR 5
#define KS 11
#define EPS_F 1e-5f
#define NLOG2E 1.44269504088896340736f
#define TW 64                 // output tile width  (blockDim.x)
#define TH 4                  // output tile height (blockDim.y)
#define SW (TW + 2 * RR)      // 74: strip width (x-halo)
#define SH (TH + 2 * RR)      // 14: t-plane height (y-halo)
#define NSTRIP (SW * TH)      // 296 strip pixels (C domain)
#define NPLANE 24             // 6 exponents x (3 channels + wsum)
#define T_OFF (NPLANE * NSTRIP)  // t-plane starts after C planes

// R7: separable reformulation. k(i,j) = t_n^{i^2} * t_n^{j^2} (t_n = the
// NEIGHBOR's masked t), so:
//   Pass V (strip x in [bx0-5, bx0+68], y in tile): for a in {0,1,4,9,16,25}:
//     C_a(y,x)   = sum_i img(y+i,x) * t(y+i,x)^(i^2+a)   (3 channels)
//     W_a(y,x)   = sum_i            t(y+i,x)^(i^2+a)
//   Pass H (output pixel): out = sum_j C_{j^2}(y,x+j),  wsum = sum_j W_{j^2}.
// Work drops ~1600 -> ~730 VALU/pixel and 484 global loads -> ~33 L1 + ~90 LDS.
// Masking: t=0 outside image kills every OOB tap (a=0 plane of OOB strip
// columns is only consumed at j=0, i.e. in-bounds output columns).
// Codegen rules from R1-R6: scalar/constexpr-indexed accumulators in
// straight-line unrolled code; NO guarded multi-output inner loop (that
// pattern spilled to VGPR=256 in R3/R4/R6 regardless of accumulator count).
__global__ __launch_bounds__(256) void gauss_psf_kernel(const float* __restrict__ image,
                                                        const float* __restrict__ psf,
                                                        float* __restrict__ out) {
    __shared__ float sh[T_OFF + SH * SW];   // 24*296 + 14*74 = 8140 f = 32.6 KB

    const int tx  = threadIdx.x;            // 0..63
    const int ty  = threadIdx.y;            // 0..3
    const int tid = ty * 64 + tx;
    const int bx0 = blockIdx.x * TW;
    const int by0 = blockIdx.y * TH;
    const int b   = blockIdx.z;

    const float* pw   = psf + (size_t)b * HH * WW;
    const float* img0 = image + (size_t)b * 3 * HH * WW;
    const float* img1 = img0 + HH * WW;
    const float* img2 = img0 + 2 * HH * WW;

    // ---- Phase 1: masked-t tile, 14 x 74 ----
#pragma unroll
    for (int base = 0; base < SH * SW; base += 256) {
        const int idx = base + tid;
        if (idx < SH * SW) {
            const int row = idx / SW, col = idx - row * SW;
            const int gy = by0 - RR + row, gx = bx0 - RR + col;
            const bool in = ((unsigned)gy < (unsigned)HH) && ((unsigned)gx < (unsigned)WW);
            const int cy = gy < 0 ? 0 : (gy > HH - 1 ? HH - 1 : gy);
            const int cx = gx < 0 ? 0 : (gx > WW - 1 ? WW - 1 : gx);
            const float w = pw[cy * WW + cx];
            const float a = -NLOG2E * __builtin_amdgcn_rcpf(fmaf(2.0f * w, w, EPS_F));
            sh[T_OFF + idx] = in ? __builtin_amdgcn_exp2f(a) : 0.0f;
        }
    }
    __syncthreads();

    // ---- Phase 2 (pass V): 296 strip pixels, 24 accumulators each ----
    for (int idx = tid; idx < NSTRIP; idx += 256) {
        const int ly = idx / SW;            // 0..3
        const int lx = idx - ly * SW;       // 0..73
        const int gx = bx0 - RR + lx;
        const int gxc = gx < 0 ? 0 : (gx > WW - 1 ? WW - 1 : gx);
        const int gy = by0 + ly;

        float accw[6], acc0[6], acc1[6], acc2[6];
#pragma unroll
        for (int ai = 0; ai < 6; ++ai) { accw[ai] = acc0[ai] = acc1[ai] = acc2[ai] = 0.0f; }

#pragma unroll
        for (int r = 0; r < KS; ++r) {
            const float t = sh[T_OFF + (ly + r) * SW + lx];    // ds_read, const off
            int ry = gy + r - RR;
            ry = ry < 0 ? 0 : (ry > HH - 1 ? HH - 1 : ry);
            const int ni = ry * WW + gxc;
            const float i0 = img0[ni];
            const float i1 = img1[ni];
            const float i2 = img2[ni];

            const float T2 = t * t, T4 = T2 * T2, T8 = T4 * T4, T16 = T8 * T8;
            const float P1 = t, P4 = T4, P9 = T8 * t, P16 = T16, P25 = T16 * P9;
            const float PA[6] = {1.0f, P1, P4, P9, P16, P25};  // t^a, constexpr-indexed
            const int ii = (r - RR) * (r - RR);                // constexpr after unroll
            const float u = ii == 0 ? 1.0f : ii == 1 ? P1 : ii == 4 ? P4
                          : ii == 9 ? P9 : ii == 16 ? P16 : P25;   // t^(i^2)

#pragma unroll
            for (int ai = 0; ai < 6; ++ai) {                   // constant trip, no guard
                const float f = u * PA[ai];                    // t^(i^2+a)
                accw[ai] += f;
                acc0[ai] = fmaf(i0, f, acc0[ai]);
                acc1[ai] = fmaf(i1, f, acc1[ai]);
                acc2[ai] = fmaf(i2, f, acc2[ai]);
            }
        }
#pragma unroll
        for (int ai = 0; ai < 6; ++ai) {                       // 24 ds_writes
            sh[(ai * 4 + 0) * NSTRIP + idx] = acc0[ai];
            sh[(ai * 4 + 1) * NSTRIP + idx] = acc1[ai];
            sh[(ai * 4 + 2) * NSTRIP + idx] = acc2[ai];
            sh[(ai * 4 + 3) * NSTRIP + idx] = accw[ai];
        }
    }
    __syncthreads();

    // ---- Phase 3 (pass H): 44 const-offset ds_reads + adds ----
    const int hb = ty * SW + tx;            // strip index of (y, x-RR) + j
    float s0 = 0.0f, s1 = 0.0f, s2 = 0.0f, sw = 0.0f;
#pragma unroll
    for (int j = 0; j < KS; ++j) {
        const int jj = (j - RR) * (j - RR);                    // constexpr
        const int ai = jj == 0 ? 0 : jj == 1 ? 1 : jj == 4 ? 2
                     : jj == 9 ? 3 : jj == 16 ? 4 : 5;
        const int base = hb + j;
        s0 += sh[(ai * 4 + 0) * NSTRIP + base];
        s1 += sh[(ai * 4 + 1) * NSTRIP + base];
        s2 += sh[(ai * 4 + 2) * NSTRIP + base];
        sw += sh[(ai * 4 + 3) * NSTRIP + base];
    }

    float inv = __builtin_amdgcn_rcpf(sw);                     // sw >= 1 (center tap)
    inv = inv * (2.0f - sw * inv);                             // Newton: ~1e-7 rel
    const int x = bx0 + tx, y = by0 + ty;
    const int oi = y * WW + x;
    float* outb = out + (size_t)b * 3 * HH * WW;
    outb[oi]               = s0 * inv;
    outb[HH * WW + oi]     = s1 * inv;
    outb[2 * HH * WW + oi] = s2 * inv;
}

extern "C" void kernel_launch(void* const* d_in, const int* in_sizes, int n_in,
                              void* d_out, int out_size, void* d_ws, size_t ws_size,
                              hipStream_t stream) {
    const float* image = (const float*)d_in[0];
    const float* psf   = (const float*)d_in[1];
    float* out = (float*)d_out;

    dim3 block(TW, TH, 1);
    dim3 grid(WW / TW, HH / TH, 4);   // 8 x 128 x 4 = 4096 blocks
    gauss_psf_kernel<<<grid, block, 0, stream>>>(image, psf, out);
}